// Round 2
// baseline (2209.509 us; speedup 1.0000x reference)
//
#include <hip/hip_runtime.h>

// VQExpert fused kernel for MI355X (gfx950).
//
// Algebraic collapse:
//   z = x @ Wc.T + bc            where Wc = W_pin@W_down  [32,128], bc = W_pin@b_down + b_pin
//   idx = argmax_c (z . C[c] - 0.5|C[c]|^2)   (== argmin d2, first-min tie-break)
//   y = Y_table[idx]             where Y_table[c] = clip((C[c]@W_pout.T+b_pout)@W_up.T+b_up, -1, 1)
//
// d_out layout (all float32): y [N*128] | indices-as-float [N] | commit_loss [1]
//
// R2: revert to R0's LDS x-staging (R1's direct loads tripled HBM traffic: FETCH 128->445MB).
//     New: lane-pair scheme. Threads t,t^1 co-own rows (t&~1, t|1):
//       - z-phase: each lane does its 16-of-32 j-half for BOTH rows (halves Wc s_load per FMA),
//         then shfl_xor(1) exchange -> full z[32] x 2 rows in VGPRs.
//       - score phase: cb+cbias staged into the reused LDS buffer; even lanes c<128, odd c>=128,
//         both rows each -> zero scalar loads in the 8192-FMA/row score loop.
//     Tie-break: strict '>' ascending within half; pair-merge prefers even half on ties = first index.

#define CODE_D 32
#define NUM_C  256
#define KCH    32
#define LSTR   36   // LDS row stride in floats (32 + 4 pad) = 144 B, 16B-aligned

// ---------------- prep kernels (rebuilt every launch; ws is re-poisoned) ------------

// grid = 18 x 256: blocks 0..15 -> Wc[32][128]; block 16 -> bc[32]; block 17 -> cbias[256]
__global__ void vq_prep1(const float* __restrict__ Wd, const float* __restrict__ bd,
                         const float* __restrict__ Wp, const float* __restrict__ bp,
                         const float* __restrict__ cb,
                         float* __restrict__ Wc, float* __restrict__ bc,
                         float* __restrict__ cbias) {
    const int t = threadIdx.x;
    const int b = blockIdx.x;
    if (b < 16) {
        const int e = b * 256 + t;
        const int j = e >> 7, k = e & 127;
        double s0 = 0.0, s1 = 0.0;
#pragma unroll 8
        for (int m = 0; m < 128; m += 2) {
            s0 += (double)Wp[j * 128 + m]     * (double)Wd[(m) * 128 + k];
            s1 += (double)Wp[j * 128 + m + 1] * (double)Wd[(m + 1) * 128 + k];
        }
        Wc[e] = (float)(s0 + s1);
    } else if (b == 16) {
        if (t < 32) {
            double s = (double)bp[t];
            for (int m = 0; m < 128; ++m) s += (double)Wp[t * 128 + m] * (double)bd[m];
            bc[t] = (float)s;
        }
    } else {
        float s = 0.f;
#pragma unroll
        for (int d = 0; d < CODE_D; ++d) { float v = cb[t * CODE_D + d]; s += v * v; }
        cbias[t] = -0.5f * s;
    }
}

__global__ void vq_prep2(const float* __restrict__ cb, const float* __restrict__ Wpo,
                         const float* __restrict__ bpo, const float* __restrict__ Wu,
                         const float* __restrict__ bu, float* __restrict__ ytab) {
    __shared__ float v[128];
    const int c = blockIdx.x;    // 256 blocks
    const int t = threadIdx.x;   // 128 threads
    float s = bpo[t];
    for (int d = 0; d < CODE_D; ++d) s += cb[c * CODE_D + d] * Wpo[t * CODE_D + d];
    v[t] = s;
    __syncthreads();
    float o = bu[t];
    for (int m = 0; m < 128; ++m) o += v[m] * Wu[t * 128 + m];
    o = fminf(fmaxf(o, -1.0f), 1.0f);
    ytab[c * 128 + t] = o;
}

// ---------------- main fused kernel ------------------------------------------------

__global__ __launch_bounds__(256, 4) void vq_main(
    const float* __restrict__ x,      // [N,128]
    const float* __restrict__ Wc,     // [32,128]
    const float* __restrict__ bc,     // [32]
    const float* __restrict__ cb,     // codebook [256,32]
    const float* __restrict__ cbias,  // [256]
    const float* __restrict__ ytab,   // [256,128]
    float* __restrict__ y,            // [N,128]
    float* __restrict__ idx_out,      // [N] (written as float values)
    float* __restrict__ loss_out,     // [1]
    int N) {
    __shared__ float lds[256 * LSTR];   // 36 KB: x-staging, then reused for cb[256][32] (8 KB)
    __shared__ float scb[NUM_C];        // cbias
    __shared__ int sidx[256];

    const int t = threadIdx.x;
    const int row0 = blockIdx.x * 256;
    const int myrow = row0 + t;

    const int tA = t & ~1;           // pair row A
    const int tB = t | 1;            // pair row B
    const bool oddlane = (t & 1);
    const int jb = (t & 1) << 4;     // my j-half base: 0 or 16

    // z accumulators: my j-half for BOTH rows of the pair
    float zA[16], zB[16];
#pragma unroll
    for (int j = 0; j < 16; ++j) { zA[j] = bc[jb + j]; zB[j] = zA[j]; }

    // ---- z = x @ Wc.T + bc, K-chunked through LDS (identical staging to R0) ----
    const int rr = t >> 3;  // 0..31
    const int qq = t & 7;   // 0..7
    for (int kc = 0; kc < 128; kc += KCH) {
#pragma unroll
        for (int i = 0; i < 8; ++i) {
            const int r = i * 32 + rr;
            const int grow = row0 + r;
            float4 v = make_float4(0.f, 0.f, 0.f, 0.f);
            if (grow < N)
                v = *reinterpret_cast<const float4*>(x + (size_t)grow * 128 + kc + qq * 4);
            *reinterpret_cast<float4*>(&lds[r * LSTR + qq * 4]) = v;
        }
        __syncthreads();
#pragma unroll
        for (int q = 0; q < KCH / 4; ++q) {
            const float4 xa = *reinterpret_cast<const float4*>(&lds[tA * LSTR + q * 4]);
            const float4 xb = *reinterpret_cast<const float4*>(&lds[tB * LSTR + q * 4]);
            const int kb = kc + q * 4;
#pragma unroll
            for (int j = 0; j < 16; ++j) {
                const float* w = Wc + (jb + j) * 128 + kb;   // block-uniform -> s_load
                zA[j] += w[0] * xa.x + w[1] * xa.y + w[2] * xa.z + w[3] * xa.w;
                zB[j] += w[0] * xb.x + w[1] * xb.y + w[2] * xb.z + w[3] * xb.w;
            }
        }
        __syncthreads();
    }

    // ---- pair-exchange j-halves -> full z[32] for both rows, in registers ----
    float zfA[32], zfB[32];
#pragma unroll
    for (int j = 0; j < 16; ++j) {
        const float p = __shfl_xor(zA[j], 1);
        zfA[j]      = oddlane ? p     : zA[j];
        zfA[j + 16] = oddlane ? zA[j] : p;
    }
#pragma unroll
    for (int j = 0; j < 16; ++j) {
        const float p = __shfl_xor(zB[j], 1);
        zfB[j]      = oddlane ? p     : zB[j];
        zfB[j + 16] = oddlane ? zB[j] : p;
    }

    // ---- stage cb (8 KB) + cbias into the now-free LDS buffer ----
#pragma unroll
    for (int i = 0; i < 8; ++i)
        reinterpret_cast<float4*>(lds)[i * 256 + t] =
            reinterpret_cast<const float4*>(cb)[i * 256 + t];
    scb[t] = cbias[t];
    __syncthreads();

    // ---- scores: even lanes scan c in [0,128), odd lanes [128,256), both rows ----
    const int cbase = (t & 1) << 7;
    float bestA = -3.0e38f, bestB = -3.0e38f;
    int iA = 0, iB = 0;
#pragma unroll 2
    for (int i = 0; i < 128; ++i) {
        const int c = cbase + i;
        const float* crow = &lds[c * CODE_D];   // broadcast (2 distinct addrs/wave)
        float sA = scb[c];
        float sB = sA;
#pragma unroll
        for (int d4 = 0; d4 < 8; ++d4) {
            const float4 cv = *reinterpret_cast<const float4*>(crow + d4 * 4);
            sA += cv.x * zfA[d4 * 4 + 0] + cv.y * zfA[d4 * 4 + 1]
                + cv.z * zfA[d4 * 4 + 2] + cv.w * zfA[d4 * 4 + 3];
            sB += cv.x * zfB[d4 * 4 + 0] + cv.y * zfB[d4 * 4 + 1]
                + cv.z * zfB[d4 * 4 + 2] + cv.w * zfB[d4 * 4 + 3];
        }
        if (sA > bestA) { bestA = sA; iA = c; }
        if (sB > bestB) { bestB = sB; iB = c; }
    }

    // ---- merge pair halves; even half (lower c) wins ties == first-index ----
    const float pBA = __shfl_xor(bestA, 1);
    const int   pIA = __shfl_xor(iA, 1);
    const float pBB = __shfl_xor(bestB, 1);
    const int   pIB = __shfl_xor(iB, 1);
    if (!oddlane) {
        sidx[tA] = (pBA > bestA) ? pIA : iA;
        sidx[tB] = (pBB > bestB) ? pIB : iB;
    }
    __syncthreads();

    if (myrow < N) idx_out[myrow] = (float)sidx[t];

    // ---- cooperative coalesced table-gather store of y ----
    const int rsub = t >> 5;  // 0..7
    const int c4 = t & 31;    // float4 column
#pragma unroll
    for (int i = 0; i < 32; ++i) {
        const int r = i * 8 + rsub;
        const int grow = row0 + r;
        if (grow < N) {
            const int ci = sidx[r];
            const float4 v = *reinterpret_cast<const float4*>(ytab + ci * 128 + c4 * 4);
            *reinterpret_cast<float4*>(y + (size_t)grow * 128 + c4 * 4) = v;
        }
    }

    if (blockIdx.x == 0 && t == 0) loss_out[0] = 0.0f;
}

// ---------------- launch -----------------------------------------------------------

extern "C" void kernel_launch(void* const* d_in, const int* in_sizes, int n_in,
                              void* d_out, int out_size, void* d_ws, size_t ws_size,
                              hipStream_t stream) {
    const float* x   = (const float*)d_in[0];
    const float* Wd  = (const float*)d_in[1];
    const float* bd  = (const float*)d_in[2];
    const float* Wp  = (const float*)d_in[3];
    const float* bp  = (const float*)d_in[4];
    const float* cb  = (const float*)d_in[5];
    const float* Wpo = (const float*)d_in[6];
    const float* bpo = (const float*)d_in[7];
    const float* Wu  = (const float*)d_in[8];
    const float* bu  = (const float*)d_in[9];

    const int N = in_sizes[0] / 128;

    // ws layout (floats): Wc[4096] | bc[32] | cbias[256] | ytab[32768]
    float* ws    = (float*)d_ws;
    float* Wc    = ws;
    float* bc    = ws + 4096;
    float* cbias = ws + 4128;
    float* ytab  = ws + 4384;

    float* y    = (float*)d_out;
    float* idxf = y + (size_t)N * 128;
    float* loss = idxf + N;

    vq_prep1<<<18, 256, 0, stream>>>(Wd, bd, Wp, bp, cb, Wc, bc, cbias);
    vq_prep2<<<NUM_C, 128, 0, stream>>>(cb, Wpo, bpo, Wu, bu, ytab);

    const int blocks = (N + 255) / 256;
    vq_main<<<blocks, 256, 0, stream>>>(x, Wc, bc, cb, cbias, ytab, y, idxf, loss, N);
}

// Round 3
// 875.975 us; speedup vs baseline: 2.5223x; 2.5223x over previous
//
#include <hip/hip_runtime.h>

// VQExpert fused kernel for MI355X (gfx950).
//
// Algebraic collapse:
//   z = x @ Wc.T + bc            where Wc = W_pin@W_down  [32,128], bc = W_pin@b_down + b_pin
//   idx = argmax_c (z . C[c] - 0.5|C[c]|^2)   (== argmin d2, first-min tie-break)
//   y = Y_table[idx]             where Y_table[c] = clip((C[c]@W_pout.T+b_pout)@W_up.T+b_up, -1, 1)
//
// d_out layout (all float32): y [N*128] | indices-as-float [N] | commit_loss [1]
//
// R3: R2's lane-pair scheme spilled (100 live floats @ launch_bounds(256,4) -> scratch,
//     5.7GB HBM). Revert to R0's one-row-per-thread structure (proven 573 us) and attack
//     its latency-hiding instead:
//      - KCH 32->16: LDS 37.9KB -> 22.5KB => 7 blocks/CU (28 waves, 87% cap) vs 4 (50%).
//      - score loop: codebook through LDS in TWO 16KB passes (broadcast same-addr b128
//        reads, conflict-free) instead of 256x9 uniform s_load chains.
//     FP accumulation orders identical to R0 => absmax unchanged.

#define CODE_D 32
#define NUM_C  256
#define KCH    16
#define LSTR   20   // LDS row stride in floats (16 + 4 pad) = 80 B; consume reads ~2-way (free)

// ---------------- prep kernels (rebuilt every launch; ws is re-poisoned) ------------

// grid = 18 x 256: blocks 0..15 -> Wc[32][128]; block 16 -> bc[32]; block 17 -> cbias[256]
__global__ void vq_prep1(const float* __restrict__ Wd, const float* __restrict__ bd,
                         const float* __restrict__ Wp, const float* __restrict__ bp,
                         const float* __restrict__ cb,
                         float* __restrict__ Wc, float* __restrict__ bc,
                         float* __restrict__ cbias) {
    const int t = threadIdx.x;
    const int b = blockIdx.x;
    if (b < 16) {
        const int e = b * 256 + t;
        const int j = e >> 7, k = e & 127;
        double s0 = 0.0, s1 = 0.0;
#pragma unroll 8
        for (int m = 0; m < 128; m += 2) {
            s0 += (double)Wp[j * 128 + m]     * (double)Wd[(m) * 128 + k];
            s1 += (double)Wp[j * 128 + m + 1] * (double)Wd[(m + 1) * 128 + k];
        }
        Wc[e] = (float)(s0 + s1);
    } else if (b == 16) {
        if (t < 32) {
            double s = (double)bp[t];
            for (int m = 0; m < 128; ++m) s += (double)Wp[t * 128 + m] * (double)bd[m];
            bc[t] = (float)s;
        }
    } else {
        float s = 0.f;
#pragma unroll
        for (int d = 0; d < CODE_D; ++d) { float v = cb[t * CODE_D + d]; s += v * v; }
        cbias[t] = -0.5f * s;
    }
}

__global__ void vq_prep2(const float* __restrict__ cb, const float* __restrict__ Wpo,
                         const float* __restrict__ bpo, const float* __restrict__ Wu,
                         const float* __restrict__ bu, float* __restrict__ ytab) {
    __shared__ float v[128];
    const int c = blockIdx.x;    // 256 blocks
    const int t = threadIdx.x;   // 128 threads
    float s = bpo[t];
    for (int d = 0; d < CODE_D; ++d) s += cb[c * CODE_D + d] * Wpo[t * CODE_D + d];
    v[t] = s;
    __syncthreads();
    float o = bu[t];
    for (int m = 0; m < 128; ++m) o += v[m] * Wu[t * 128 + m];
    o = fminf(fmaxf(o, -1.0f), 1.0f);
    ytab[c * 128 + t] = o;
}

// ---------------- main fused kernel ------------------------------------------------

__global__ __launch_bounds__(256, 6) void vq_main(
    const float* __restrict__ x,      // [N,128]
    const float* __restrict__ Wc,     // [32,128]
    const float* __restrict__ bc,     // [32]
    const float* __restrict__ cb,     // codebook [256,32]
    const float* __restrict__ cbias,  // [256]
    const float* __restrict__ ytab,   // [256,128]
    float* __restrict__ y,            // [N,128]
    float* __restrict__ idx_out,      // [N] (written as float values)
    float* __restrict__ loss_out,     // [1]
    int N) {
    __shared__ float lds[256 * LSTR];   // 20 KB: x-staging chunks, then 2x 16KB cb passes
    __shared__ float scb[NUM_C];        // cbias
    __shared__ int sidx[256];

    const int t = threadIdx.x;
    const int row0 = blockIdx.x * 256;
    const int myrow = row0 + t;

    float z[CODE_D];
#pragma unroll
    for (int j = 0; j < CODE_D; ++j) z[j] = bc[j];

    scb[t] = cbias[t];   // stage cbias once (consumed after a later barrier)

    // ---- z = x @ Wc.T + bc, K-chunked through LDS (16-wide chunks, 8 chunks) ----
    const int rr = t >> 2;  // 0..63 : staging row group
    const int qq = t & 3;   // 0..3  : float4 quad within row chunk
    for (int kc = 0; kc < 128; kc += KCH) {
#pragma unroll
        for (int i = 0; i < 4; ++i) {
            const int r = i * 64 + rr;
            const int grow = row0 + r;
            float4 v = make_float4(0.f, 0.f, 0.f, 0.f);
            if (grow < N)
                v = *reinterpret_cast<const float4*>(x + (size_t)grow * 128 + kc + qq * 4);
            *reinterpret_cast<float4*>(&lds[r * LSTR + qq * 4]) = v;
        }
        __syncthreads();
        // consume own row's chunk; Wc is block-uniform -> s_load (same order as R0)
#pragma unroll
        for (int q = 0; q < KCH / 4; ++q) {
            const float4 xv = *reinterpret_cast<const float4*>(&lds[t * LSTR + q * 4]);
            const int kb = kc + q * 4;
#pragma unroll
            for (int j = 0; j < CODE_D; ++j) {
                const float* w = Wc + j * 128 + kb;
                z[j] += w[0] * xv.x + w[1] * xv.y + w[2] * xv.z + w[3] * xv.w;
            }
        }
        __syncthreads();
    }

    // ---- scores via LDS-broadcast codebook, two 128-code passes ----
    float best = -3.0e38f;
    int besti = 0;
#pragma unroll
    for (int pass = 0; pass < 2; ++pass) {
        // stage 128 codes (16 KB) into the staging buffer: 4 float4 per thread, coalesced
        const float4* cb4 = reinterpret_cast<const float4*>(cb) + pass * 1024;
#pragma unroll
        for (int i = 0; i < 4; ++i)
            reinterpret_cast<float4*>(lds)[i * 256 + t] = cb4[i * 256 + t];
        __syncthreads();

        const int cb0 = pass << 7;
#pragma unroll 4
        for (int i = 0; i < 128; ++i) {
            const int c = cb0 + i;
            const float* crow = &lds[i * CODE_D];   // same addr all lanes -> broadcast
            float s0 = 0.f, s1 = 0.f, s2 = 0.f, s3 = 0.f;
#pragma unroll
            for (int d = 0; d < CODE_D; d += 4) {
                s0 += crow[d + 0] * z[d + 0];
                s1 += crow[d + 1] * z[d + 1];
                s2 += crow[d + 2] * z[d + 2];
                s3 += crow[d + 3] * z[d + 3];
            }
            const float s = ((s0 + s1) + (s2 + s3)) + scb[c];
            if (s > best) { best = s; besti = c; }   // strict > , ascending c => first-min
        }
        __syncthreads();
    }

    sidx[t] = besti;
    if (myrow < N) idx_out[myrow] = (float)besti;
    __syncthreads();

    // ---- cooperative coalesced table-gather store of y ----
    const int rsub = t >> 5;  // 0..7
    const int c4 = t & 31;    // float4 column
#pragma unroll
    for (int i = 0; i < 32; ++i) {
        const int r = i * 8 + rsub;
        const int grow = row0 + r;
        if (grow < N) {
            const int ci = sidx[r];
            const float4 v = *reinterpret_cast<const float4*>(ytab + ci * 128 + c4 * 4);
            *reinterpret_cast<float4*>(y + (size_t)grow * 128 + c4 * 4) = v;
        }
    }

    if (blockIdx.x == 0 && t == 0) loss_out[0] = 0.0f;
}

// ---------------- launch -----------------------------------------------------------

extern "C" void kernel_launch(void* const* d_in, const int* in_sizes, int n_in,
                              void* d_out, int out_size, void* d_ws, size_t ws_size,
                              hipStream_t stream) {
    const float* x   = (const float*)d_in[0];
    const float* Wd  = (const float*)d_in[1];
    const float* bd  = (const float*)d_in[2];
    const float* Wp  = (const float*)d_in[3];
    const float* bp  = (const float*)d_in[4];
    const float* cb  = (const float*)d_in[5];
    const float* Wpo = (const float*)d_in[6];
    const float* bpo = (const float*)d_in[7];
    const float* Wu  = (const float*)d_in[8];
    const float* bu  = (const float*)d_in[9];

    const int N = in_sizes[0] / 128;

    // ws layout (floats): Wc[4096] | bc[32] | cbias[256] | ytab[32768]
    float* ws    = (float*)d_ws;
    float* Wc    = ws;
    float* bc    = ws + 4096;
    float* cbias = ws + 4128;
    float* ytab  = ws + 4384;

    float* y    = (float*)d_out;
    float* idxf = y + (size_t)N * 128;
    float* loss = idxf + N;

    vq_prep1<<<18, 256, 0, stream>>>(Wd, bd, Wp, bp, cb, Wc, bc, cbias);
    vq_prep2<<<NUM_C, 128, 0, stream>>>(cb, Wpo, bpo, Wu, bu, ytab);

    const int blocks = (N + 255) / 256;
    vq_main<<<blocks, 256, 0, stream>>>(x, Wc, bc, cb, cbias, ytab, y, idxf, loss, N);
}